// Round 6
// baseline (153.179 us; speedup 1.0000x reference)
//
#include <hip/hip_runtime.h>

// B=4, P=2048, N=8192, QD=CD=INNER=512, HEADS=8, DH=64, HC=WC=32, L=1024
// STRIDE=8 -> 17x17 clipped rectangle mask

typedef __attribute__((ext_vector_type(8))) short bf16x8;
typedef __attribute__((ext_vector_type(4))) float f32x4;

#define SCL 0.18033688f   // 0.125 * log2(e): softmax in exp2 domain, folded into Q

__device__ __forceinline__ unsigned short f2bf(float x) {
  union { float f; unsigned int u; } v; v.f = x;
  unsigned int r = v.u + 0x7FFFu + ((v.u >> 16) & 1u);  // RNE
  return (unsigned short)(r >> 16);
}

__device__ __forceinline__ unsigned int pk2bf(float a, float b) {
  return (unsigned)f2bf(a) | ((unsigned)f2bf(b) << 16);
}

__device__ __forceinline__ float fexp2(float x) {
#if __has_builtin(__builtin_amdgcn_exp2f)
  return __builtin_amdgcn_exp2f(x);
#else
  return exp2f(x);
#endif
}

// ---- prep: weights -> N-major bf16; plus Vt ones/zeros pad rows (d=64..79) ----
__global__ __launch_bounds__(256) void prep_w(const float* __restrict__ Wq, const float* __restrict__ Wk,
                                              const float* __restrict__ Wv, const float* __restrict__ Wo,
                                              unsigned short* __restrict__ Wqt, unsigned short* __restrict__ Wkt,
                                              unsigned short* __restrict__ Wvt, unsigned short* __restrict__ Wot,
                                              unsigned short* __restrict__ Vt) {
  int i = blockIdx.x * 256 + threadIdx.x;     // < 4*512*512 + 524288
  if (i < 1048576) {
    int wsel = i >> 18;
    int r = i & 262143;
    int k = r >> 9, n = r & 511;
    const float* W = (wsel == 0) ? Wq : (wsel == 1) ? Wk : (wsel == 2) ? Wv : Wo;
    unsigned short* Wt = (wsel == 0) ? Wqt : (wsel == 1) ? Wkt : (wsel == 2) ? Wvt : Wot;
    Wt[n * 512 + k] = f2bf(W[r]);
  } else {
    int e = i - 1048576;            // < 32*16*1024
    int bh = e >> 14;
    int r16 = (e >> 10) & 15;
    int j = e & 1023;
    Vt[((long)bh * 80 + 64 + r16) * 1024 + j] = (r16 == 0) ? (unsigned short)0x3F80 : (unsigned short)0;
  }
}

// ---- fused Q|K|V projections with input prep ----
// bx<512: Q (M=8192, Q pre-scaled by SCL). bx>=512: K|V (M=4096; V written transposed,
// d-major, keys interleaved within 64-tiles: pos = (j&~63) | ((j&15)<<2) | ((j>>4)&3)).
__global__ __launch_bounds__(256) void gemm_qkv(const float* __restrict__ feats,
                                                const int* __restrict__ coords,
                                                const float* __restrict__ pos_emb,
                                                const float* __restrict__ ctx,
                                                const float* __restrict__ ctx_pos,
                                                const unsigned short* __restrict__ Wqt,
                                                const unsigned short* __restrict__ Wkt,
                                                const unsigned short* __restrict__ Wvt,
                                                unsigned short* __restrict__ Qb,
                                                unsigned short* __restrict__ Kb,
                                                unsigned short* __restrict__ Vt) {
  __shared__ unsigned short As[64][40];
  __shared__ unsigned short Bs[128][40];
  __shared__ int pidx[64];
  const int t = threadIdx.x, l = t & 63, wid = t >> 6;
  const int wr = (wid >> 1) << 5, wc = (wid & 1) << 6;
  const int bx = blockIdx.x;
  const bool isQ = bx < 512;
  long tm; const unsigned short* Bt; bool isV = false; int nt;
  if (isQ) {
    tm = (long)(bx >> 2) * 64;
    nt = bx & 3;
    Bt = Wqt + (long)nt * 65536;
    if (t < 64) {
      long q = tm + t;
      pidx[t] = ((coords[2 * q] >> 3) << 6) + (coords[2 * q + 1] >> 3);
    }
    __syncthreads();
  } else {
    const int kvx = bx - 512;
    tm = (long)(kvx >> 3) * 64;
    const int y = kvx & 7;
    isV = y >= 4; nt = y & 3;
    Bt = (isV ? Wvt : Wkt) + (long)nt * 65536;
  }
  f32x4 acc[2][4] = {};
  const int lr = l & 15, lk = (l >> 4) << 3;
  for (int k0 = 0; k0 < 512; k0 += 32) {
#pragma unroll
    for (int p = 0; p < 2; ++p) {               // A: 64x32 f32 + pos add -> bf16
      int e = t + (p << 8);
      int row = e >> 3, kg = (e & 7) << 2;
      float4 a, pv;
      if (isQ) {
        a = *(const float4*)(feats + (tm + row) * 512 + k0 + kg);
        pv = *(const float4*)(pos_emb + (size_t)pidx[row] * 512 + k0 + kg);
      } else {
        long ar = tm + row;
        a = *(const float4*)(ctx + ar * 512 + k0 + kg);
        pv = *(const float4*)(ctx_pos + (size_t)(ar & 1023) * 512 + k0 + kg);
      }
      uint2 o;
      o.x = pk2bf(a.x + pv.x, a.y + pv.y);
      o.y = pk2bf(a.z + pv.z, a.w + pv.w);
      *(uint2*)(&As[row][kg]) = o;
    }
#pragma unroll
    for (int p = 0; p < 2; ++p) {               // B: 128x32 bf16
      int e = t + (p << 8);
      int row = e >> 2, kg = (e & 3) << 3;
      *(int4*)(&Bs[row][kg]) = *(const int4*)(Bt + (long)row * 512 + k0 + kg);
    }
    __syncthreads();
    bf16x8 af[2], bfr[4];
#pragma unroll
    for (int i = 0; i < 2; ++i) af[i]  = *(const bf16x8*)(&As[wr + i * 16 + lr][lk]);
#pragma unroll
    for (int i = 0; i < 4; ++i) bfr[i] = *(const bf16x8*)(&Bs[wc + i * 16 + lr][lk]);
#pragma unroll
    for (int mi = 0; mi < 2; ++mi)
#pragma unroll
      for (int ni = 0; ni < 4; ++ni)
        acc[mi][ni] = __builtin_amdgcn_mfma_f32_16x16x32_bf16(af[mi], bfr[ni], acc[mi][ni], 0, 0, 0);
    __syncthreads();
  }
  const int lq = (l >> 4) << 2;
#pragma unroll
  for (int mi = 0; mi < 2; ++mi)
#pragma unroll
    for (int ni = 0; ni < 4; ++ni) {
      int cn = nt * 128 + wc + ni * 16 + lr;
      long r0 = tm + wr + mi * 16 + lq;
      if (isQ) {
#pragma unroll
        for (int r = 0; r < 4; ++r)
          Qb[(r0 + r) * 512 + cn] = f2bf(acc[mi][ni][r] * SCL);
      } else if (!isV) {
#pragma unroll
        for (int r = 0; r < 4; ++r)
          Kb[(r0 + r) * 512 + cn] = f2bf(acc[mi][ni][r]);
      } else {
        int h = cn >> 6, d = cn & 63;
#pragma unroll
        for (int r = 0; r < 4; ++r) {
          long row = r0 + r;
          int b = (int)(row >> 10), j = (int)(row & 1023);
          int jp = (j & ~63) | ((j & 15) << 2) | ((j >> 4) & 3);
          Vt[((long)(b * 8 + h) * 80 + d) * 1024 + jp] = f2bf(acc[mi][ni][r]);
        }
      }
    }
}

// ---- MFMA masked flash attention ----
// grid (32, 32): x = q-tile of 64 within batch, y = b*8+h.
// 4 waves: qg = w>>1 (32 queries), ks = w&1 (512-key half). No online max (scores
// bounded); l computed via ones-column (df=4) of padded Vt. 2-way combine in LDS.
__global__ __launch_bounds__(256, 3) void attn_mfma(const unsigned short* __restrict__ Qb,
                                                    const unsigned short* __restrict__ Kb,
                                                    const unsigned short* __restrict__ Vt,
                                                    const int* __restrict__ coords,
                                                    unsigned short* __restrict__ Abf) {
  union __align__(16) ShMem {
    unsigned short P[4][32][72];   // per-wave P tile (col' = 4*lc + kf, matches Vt permute)
    float O[2][32][68];            // combine buffer (aliased; used after barrier)
  };
  __shared__ ShMem sh;
  __shared__ float lcmb[2][2][32];
  const int t = threadIdx.x, w = t >> 6, l = t & 63;
  const int g = l >> 4, lc = l & 15;
  const int qg = w >> 1, ks = w & 1;
  const int bh = blockIdx.y, b = bh >> 3, h = bh & 7;
  const long qrow0 = (long)b * 2048 + blockIdx.x * 64 + qg * 32;

  // 32-bit row/col bitmasks for the 8 query-rows this lane reduces
  int rm[8], cm[8];
#pragma unroll
  for (int qf = 0; qf < 2; ++qf)
#pragma unroll
    for (int r = 0; r < 4; ++r) {
      long qq = qrow0 + qf * 16 + g * 4 + r;
      int cr = (int)rintf((float)coords[2 * qq] * 0.0625f);      // round-half-even = jnp.round
      int cc = (int)rintf((float)coords[2 * qq + 1] * 0.0625f);
      int rlo = max(0, cr - 8), rhi = min(31, cr + 8);
      int clo = max(0, cc - 8), chi = min(31, cc + 8);
      rm[qf * 4 + r] = (int)((((unsigned)1 << (rhi - rlo + 1)) - 1) << rlo);
      cm[qf * 4 + r] = (int)((((unsigned)1 << (chi - clo + 1)) - 1) << clo);
    }

  bf16x8 qfr[2][2];
#pragma unroll
  for (int qf = 0; qf < 2; ++qf)
#pragma unroll
    for (int dc = 0; dc < 2; ++dc)
      qfr[qf][dc] = *(const bf16x8*)(Qb + (qrow0 + qf * 16 + lc) * 512 + h * 64 + dc * 32 + g * 8);

  f32x4 po[2][5] = {};   // [qf][df]; df=4 is the ones-column (row-sum l at lanes lc==0)

  const unsigned short* Kbb = Kb + ((long)b * 1024) * 512 + h * 64;
  const unsigned short* Vtb = Vt + (long)bh * 80 * 1024;

  for (int kt = 0; kt < 8; ++kt) {
    const int kb = ks * 512 + kt * 64;
    bf16x8 kfr[4][2];
#pragma unroll
    for (int kf = 0; kf < 4; ++kf)
#pragma unroll
      for (int dc = 0; dc < 2; ++dc)
        kfr[kf][dc] = *(const bf16x8*)(Kbb + (long)(kb + kf * 16 + lc) * 512 + dc * 32 + g * 8);

    // S = (Q*SCL) K^T
    f32x4 sv[2][4];
#pragma unroll
    for (int qf = 0; qf < 2; ++qf)
#pragma unroll
      for (int kf = 0; kf < 4; ++kf) {
        f32x4 a = {};
        a = __builtin_amdgcn_mfma_f32_16x16x32_bf16(qfr[qf][0], kfr[kf][0], a, 0, 0, 0);
        a = __builtin_amdgcn_mfma_f32_16x16x32_bf16(qfr[qf][1], kfr[kf][1], a, 0, 0, 0);
        sv[qf][kf] = a;
      }

    // mask (cndmask only; scale pre-folded into Q), then exp2
#pragma unroll
    for (int kf = 0; kf < 4; ++kf) {
      int j = kb + kf * 16 + lc;
      int jr = j >> 5, jc = j & 31;
#pragma unroll
      for (int qf = 0; qf < 2; ++qf)
#pragma unroll
        for (int r = 0; r < 4; ++r) {
          bool ok = ((rm[qf * 4 + r] >> jr) & (cm[qf * 4 + r] >> jc) & 1) != 0;
          float s = ok ? sv[qf][kf][r] : -1.0e30f;
          sv[qf][kf][r] = fexp2(s);
        }
    }

    // V^T fragments (df=4: ones-column rows)
    bf16x8 vfr[5][2];
#pragma unroll
    for (int df = 0; df < 5; ++df)
#pragma unroll
      for (int kc = 0; kc < 2; ++kc)
        vfr[df][kc] = *(const bf16x8*)(Vtb + (long)(df * 16 + lc) * 1024 + kb + kc * 32 + g * 8);

    // P pack -> LDS b64 stores at col' = 4*lc (+kf), wave-private
#pragma unroll
    for (int qf = 0; qf < 2; ++qf)
#pragma unroll
      for (int r = 0; r < 4; ++r) {
        uint2 pk;
        pk.x = pk2bf(sv[qf][0][r], sv[qf][1][r]);
        pk.y = pk2bf(sv[qf][2][r], sv[qf][3][r]);
        *(uint2*)(&sh.P[w][qf * 16 + g * 4 + r][4 * lc]) = pk;
      }

#pragma unroll
    for (int qf = 0; qf < 2; ++qf) {
      bf16x8 pa0 = *(const bf16x8*)(&sh.P[w][qf * 16 + lc][g * 8]);
      bf16x8 pa1 = *(const bf16x8*)(&sh.P[w][qf * 16 + lc][32 + g * 8]);
#pragma unroll
      for (int df = 0; df < 5; ++df) {
        po[qf][df] = __builtin_amdgcn_mfma_f32_16x16x32_bf16(pa0, vfr[df][0], po[qf][df], 0, 0, 0);
        po[qf][df] = __builtin_amdgcn_mfma_f32_16x16x32_bf16(pa1, vfr[df][1], po[qf][df], 0, 0, 0);
      }
    }
  }

  // ---- 2-way combine across key-halves ----
  if (lc == 0) {
#pragma unroll
    for (int qf = 0; qf < 2; ++qf)
#pragma unroll
      for (int r = 0; r < 4; ++r)
        lcmb[ks][qg][qf * 16 + g * 4 + r] = po[qf][4][r];
  }
  __syncthreads();                 // all P-tile use complete; O aliases P
  if (ks == 1) {
#pragma unroll
    for (int qf = 0; qf < 2; ++qf)
#pragma unroll
      for (int df = 0; df < 4; ++df)
#pragma unroll
        for (int r = 0; r < 4; ++r)
          sh.O[qg][qf * 16 + g * 4 + r][df * 16 + lc] = po[qf][df][r];
  }
  __syncthreads();
  if (ks == 0) {
#pragma unroll
    for (int qf = 0; qf < 2; ++qf)
#pragma unroll
      for (int r = 0; r < 4; ++r) {
        int row = qf * 16 + g * 4 + r;
        float inv = 1.0f / (lcmb[0][qg][row] + lcmb[1][qg][row]);
        long qr = qrow0 + row;
#pragma unroll
        for (int df = 0; df < 4; ++df)
          Abf[qr * 512 + h * 64 + df * 16 + lc] =
              f2bf((po[qf][df][r] + sh.O[qg][row][df * 16 + lc]) * inv);
      }
  }
}

// ---- output projection: out = Abf @ Wot^T + bo (fp32 out) ----
__global__ __launch_bounds__(256) void gemm_o(const unsigned short* __restrict__ A,
                                              const unsigned short* __restrict__ Bt,
                                              float* __restrict__ C,
                                              const float* __restrict__ bias) {
  __shared__ unsigned short As[64][40];
  __shared__ unsigned short Bs[128][40];
  const int t = threadIdx.x, l = t & 63, wid = t >> 6;
  const int wr = (wid >> 1) << 5;
  const int wc = (wid & 1) << 6;
  const long tm = (long)blockIdx.x * 64;
  const long tn = (long)blockIdx.y * 128;
  f32x4 acc[2][4] = {};
  const int lr = l & 15, lk = (l >> 4) << 3;
  for (int k0 = 0; k0 < 512; k0 += 32) {
    {
      int e = t;
      int row = e >> 2, kg = (e & 3) << 3;
      if (row < 64)
        *(int4*)(&As[row][kg]) = *(const int4*)(A + (tm + row) * 512 + k0 + kg);
    }
#pragma unroll
    for (int p = 0; p < 2; ++p) {
      int e = t + (p << 8);
      int row = e >> 2, kg = (e & 3) << 3;
      *(int4*)(&Bs[row][kg]) = *(const int4*)(Bt + (tn + row) * 512 + k0 + kg);
    }
    __syncthreads();
    bf16x8 af[2], bfr[4];
#pragma unroll
    for (int i = 0; i < 2; ++i) af[i]  = *(const bf16x8*)(&As[wr + i * 16 + lr][lk]);
#pragma unroll
    for (int i = 0; i < 4; ++i) bfr[i] = *(const bf16x8*)(&Bs[wc + i * 16 + lr][lk]);
#pragma unroll
    for (int mi = 0; mi < 2; ++mi)
#pragma unroll
      for (int ni = 0; ni < 4; ++ni)
        acc[mi][ni] = __builtin_amdgcn_mfma_f32_16x16x32_bf16(af[mi], bfr[ni], acc[mi][ni], 0, 0, 0);
    __syncthreads();
  }
  const int lq = (l >> 4) << 2;
#pragma unroll
  for (int mi = 0; mi < 2; ++mi)
#pragma unroll
    for (int ni = 0; ni < 4; ++ni) {
      long col = tn + wc + ni * 16 + lr;
      float bv = bias[col];
      long r0 = tm + wr + mi * 16 + lq;
#pragma unroll
      for (int r = 0; r < 4; ++r)
        C[(r0 + r) * 512 + col] = acc[mi][ni][r] + bv;
    }
}

extern "C" void kernel_launch(void* const* d_in, const int* in_sizes, int n_in,
                              void* d_out, int out_size, void* d_ws, size_t ws_size,
                              hipStream_t stream) {
  (void)in_sizes; (void)n_in; (void)out_size; (void)ws_size;
  const float* feats   = (const float*)d_in[0];
  const int*   coords  = (const int*)d_in[1];
  const float* ctx     = (const float*)d_in[2];
  const float* Wq      = (const float*)d_in[3];
  const float* Wk      = (const float*)d_in[4];
  const float* Wv      = (const float*)d_in[5];
  const float* Wo      = (const float*)d_in[6];
  const float* bo      = (const float*)d_in[7];
  const float* pos_emb = (const float*)d_in[8];
  const float* ctx_pos = (const float*)d_in[9];
  float* out = (float*)d_out;
  char* ws = (char*)d_ws;

  unsigned short* Wqt = (unsigned short*)(ws);               //   524,288
  unsigned short* Wkt = (unsigned short*)(ws + 524288);
  unsigned short* Wvt = (unsigned short*)(ws + 1048576);
  unsigned short* Wot = (unsigned short*)(ws + 1572864);
  unsigned short* Qb  = (unsigned short*)(ws + 2097152);     // 8,388,608
  unsigned short* Kb  = (unsigned short*)(ws + 10485760);    // 4,194,304
  unsigned short* Vt  = (unsigned short*)(ws + 14680064);    // 5,242,880 (80 d-rows)
  unsigned short* Abf = (unsigned short*)(ws + 19922944);    // 8,388,608 (end 28,311,552)

  prep_w  <<<6144, 256, 0, stream>>>(Wq, Wk, Wv, Wo, Wqt, Wkt, Wvt, Wot, Vt);
  gemm_qkv<<<1024, 256, 0, stream>>>(feats, coords, pos_emb, ctx, ctx_pos,
                                     Wqt, Wkt, Wvt, Qb, Kb, Vt);
  attn_mfma<<<dim3(32, 32), 256, 0, stream>>>(Qb, Kb, Vt, coords, Abf);
  gemm_o  <<<dim3(128, 4), 256, 0, stream>>>(Abf, Wot, out, bo);
}

// Round 7
// 108.157 us; speedup vs baseline: 1.4163x; 1.4163x over previous
//
#include <hip/hip_runtime.h>

// B=4, P=2048, N=8192, QD=CD=INNER=512, HEADS=8, DH=64, HC=WC=32, L=1024
// STRIDE=8 -> 17x17 clipped rectangle mask

typedef __attribute__((ext_vector_type(8))) short bf16x8;
typedef __attribute__((ext_vector_type(4))) float f32x4;

#define SCL 0.18033688f   // 0.125 * log2(e): softmax in exp2 domain, folded into Q

__device__ __forceinline__ unsigned short f2bf(float x) {
  union { float f; unsigned int u; } v; v.f = x;
  unsigned int r = v.u + 0x7FFFu + ((v.u >> 16) & 1u);  // RNE
  return (unsigned short)(r >> 16);
}

__device__ __forceinline__ unsigned int pk2bf(float a, float b) {
  return (unsigned)f2bf(a) | ((unsigned)f2bf(b) << 16);
}

__device__ __forceinline__ float fexp2(float x) {
#if __has_builtin(__builtin_amdgcn_exp2f)
  return __builtin_amdgcn_exp2f(x);
#else
  return exp2f(x);
#endif
}

// LDS tile swizzle: [row][chunk-of-16B] -> byte offset, XOR bank spread (G4)
__device__ __forceinline__ int swzb(int row, int chk) {
  return row * 128 + ((chk * 16) ^ ((row & 7) << 4));
}

// ---- prep: weights -> N-major bf16 (Wt[n][k] = W[k][n]) ----
__global__ __launch_bounds__(256) void prep_w(const float* __restrict__ Wq, const float* __restrict__ Wk,
                                              const float* __restrict__ Wv, const float* __restrict__ Wo,
                                              unsigned short* __restrict__ Wqt, unsigned short* __restrict__ Wkt,
                                              unsigned short* __restrict__ Wvt, unsigned short* __restrict__ Wot) {
  int i = blockIdx.x * 256 + threadIdx.x;     // < 4*512*512
  int wsel = i >> 18;
  int r = i & 262143;
  int k = r >> 9, n = r & 511;
  const float* W = (wsel == 0) ? Wq : (wsel == 1) ? Wk : (wsel == 2) ? Wv : Wo;
  unsigned short* Wt = (wsel == 0) ? Wqt : (wsel == 1) ? Wkt : (wsel == 2) ? Wvt : Wot;
  Wt[n * 512 + k] = f2bf(W[r]);
}

// ---- fused Q|K|V projections with input prep ----
// bx<512: Q (M=8192, Q pre-scaled by SCL). bx>=512: K|V (M=4096; V written transposed,
// d-major, keys interleaved within 64-tiles: pos = (j&~63) | ((j&15)<<2) | ((j>>4)&3)).
__global__ __launch_bounds__(256) void gemm_qkv(const float* __restrict__ feats,
                                                const int* __restrict__ coords,
                                                const float* __restrict__ pos_emb,
                                                const float* __restrict__ ctx,
                                                const float* __restrict__ ctx_pos,
                                                const unsigned short* __restrict__ Wqt,
                                                const unsigned short* __restrict__ Wkt,
                                                const unsigned short* __restrict__ Wvt,
                                                unsigned short* __restrict__ Qb,
                                                unsigned short* __restrict__ Kb,
                                                unsigned short* __restrict__ Vt) {
  __shared__ unsigned short As[64][40];
  __shared__ unsigned short Bs[128][40];
  __shared__ int pidx[64];
  const int t = threadIdx.x, l = t & 63, wid = t >> 6;
  const int wr = (wid >> 1) << 5, wc = (wid & 1) << 6;
  const int bx = blockIdx.x;
  const bool isQ = bx < 512;
  long tm; const unsigned short* Bt; bool isV = false; int nt;
  if (isQ) {
    tm = (long)(bx >> 2) * 64;
    nt = bx & 3;
    Bt = Wqt + (long)nt * 65536;
    if (t < 64) {
      long q = tm + t;
      pidx[t] = ((coords[2 * q] >> 3) << 6) + (coords[2 * q + 1] >> 3);
    }
    __syncthreads();
  } else {
    const int kvx = bx - 512;
    tm = (long)(kvx >> 3) * 64;
    const int y = kvx & 7;
    isV = y >= 4; nt = y & 3;
    Bt = (isV ? Wvt : Wkt) + (long)nt * 65536;
  }
  f32x4 acc[2][4] = {};
  const int lr = l & 15, lk = (l >> 4) << 3;
  for (int k0 = 0; k0 < 512; k0 += 32) {
#pragma unroll
    for (int p = 0; p < 2; ++p) {               // A: 64x32 f32 + pos add -> bf16
      int e = t + (p << 8);
      int row = e >> 3, kg = (e & 7) << 2;
      float4 a, pv;
      if (isQ) {
        a = *(const float4*)(feats + (tm + row) * 512 + k0 + kg);
        pv = *(const float4*)(pos_emb + (size_t)pidx[row] * 512 + k0 + kg);
      } else {
        long ar = tm + row;
        a = *(const float4*)(ctx + ar * 512 + k0 + kg);
        pv = *(const float4*)(ctx_pos + (size_t)(ar & 1023) * 512 + k0 + kg);
      }
      uint2 o;
      o.x = pk2bf(a.x + pv.x, a.y + pv.y);
      o.y = pk2bf(a.z + pv.z, a.w + pv.w);
      *(uint2*)(&As[row][kg]) = o;
    }
#pragma unroll
    for (int p = 0; p < 2; ++p) {               // B: 128x32 bf16
      int e = t + (p << 8);
      int row = e >> 2, kg = (e & 3) << 3;
      *(int4*)(&Bs[row][kg]) = *(const int4*)(Bt + (long)row * 512 + k0 + kg);
    }
    __syncthreads();
    bf16x8 af[2], bfr[4];
#pragma unroll
    for (int i = 0; i < 2; ++i) af[i]  = *(const bf16x8*)(&As[wr + i * 16 + lr][lk]);
#pragma unroll
    for (int i = 0; i < 4; ++i) bfr[i] = *(const bf16x8*)(&Bs[wc + i * 16 + lr][lk]);
#pragma unroll
    for (int mi = 0; mi < 2; ++mi)
#pragma unroll
      for (int ni = 0; ni < 4; ++ni)
        acc[mi][ni] = __builtin_amdgcn_mfma_f32_16x16x32_bf16(af[mi], bfr[ni], acc[mi][ni], 0, 0, 0);
    __syncthreads();
  }
  const int lq = (l >> 4) << 2;
#pragma unroll
  for (int mi = 0; mi < 2; ++mi)
#pragma unroll
    for (int ni = 0; ni < 4; ++ni) {
      int cn = nt * 128 + wc + ni * 16 + lr;
      long r0 = tm + wr + mi * 16 + lq;
      if (isQ) {
#pragma unroll
        for (int r = 0; r < 4; ++r)
          Qb[(r0 + r) * 512 + cn] = f2bf(acc[mi][ni][r] * SCL);
      } else if (!isV) {
#pragma unroll
        for (int r = 0; r < 4; ++r)
          Kb[(r0 + r) * 512 + cn] = f2bf(acc[mi][ni][r]);
      } else {
        int h = cn >> 6, d = cn & 63;
#pragma unroll
        for (int r = 0; r < 4; ++r) {
          long row = r0 + r;
          int b = (int)(row >> 10), j = (int)(row & 1023);
          int jp = (j & ~63) | ((j & 15) << 2) | ((j >> 4) & 3);
          Vt[((long)(b * 8 + h) * 64 + d) * 1024 + jp] = f2bf(acc[mi][ni][r]);
        }
      }
    }
}

// ---- MFMA masked flash attention, LDS-staged K/V ----
// grid (16, 32): x = q-tile of 128 (4 waves x 32q), y = b*8+h. 16 key-tiles of 64.
// K/V tiles reg-staged with coalesced loads -> XOR-swizzled double-buffered LDS.
__global__ __launch_bounds__(256) void attn_mfma(const unsigned short* __restrict__ Qb,
                                                 const unsigned short* __restrict__ Kb,
                                                 const unsigned short* __restrict__ Vt,
                                                 const int* __restrict__ coords,
                                                 unsigned short* __restrict__ Abf) {
  __shared__ char Kl[2][8192];                 // 64 keys x 64 d (swizzled)
  __shared__ char Vl[2][8192];                 // 64 d x 64 keys' (swizzled, keys interleaved)
  __shared__ char Ol[2048];                    // 16 x 64: row0 = ones (row-sum column)
  __shared__ unsigned short Plds[4][32][72];   // per-wave P (col' = 4*lc + kf)
  const int t = threadIdx.x, w = t >> 6, l = t & 63;
  const int g = l >> 4, lc = l & 15;
  const int bh = blockIdx.y, b = bh >> 3, h = bh & 7;
  const long qrow0 = (long)b * 2048 + blockIdx.x * 128 + w * 32;

  // rect bitmasks for the 8 query-rows this lane reduces
  int rm[8], cm[8];
#pragma unroll
  for (int qf = 0; qf < 2; ++qf)
#pragma unroll
    for (int r = 0; r < 4; ++r) {
      long qq = qrow0 + qf * 16 + g * 4 + r;
      int cr = (int)rintf((float)coords[2 * qq] * 0.0625f);      // round-half-even = jnp.round
      int cc = (int)rintf((float)coords[2 * qq + 1] * 0.0625f);
      int rlo = max(0, cr - 8), rhi = min(31, cr + 8);
      int clo = max(0, cc - 8), chi = min(31, cc + 8);
      rm[qf * 4 + r] = (int)((((unsigned)1 << (rhi - rlo + 1)) - 1) << rlo);
      cm[qf * 4 + r] = (int)((((unsigned)1 << (chi - clo + 1)) - 1) << clo);
    }

  bf16x8 qfr[2][2];
#pragma unroll
  for (int qf = 0; qf < 2; ++qf)
#pragma unroll
    for (int dc = 0; dc < 2; ++dc)
      qfr[qf][dc] = *(const bf16x8*)(Qb + (qrow0 + qf * 16 + lc) * 512 + h * 64 + dc * 32 + g * 8);

  // staging geometry: thread t covers rows srow, srow+32 (16B chunk schk)
  const int srow = t >> 3, schk = t & 7;
  const unsigned short* Kg = Kb + ((long)b * 1024) * 512 + h * 64;   // key j -> Kg[j*512 + d]
  const unsigned short* Vg = Vt + ((long)bh * 64) * 1024;            // d -> Vg[d*1024 + j']

  // ones region: row 0 = 1.0, rows 1..15 = 0 (swizzled like data tiles)
  if (t < 128) {
    int r = t >> 3, c = t & 7;
    unsigned short vv = (r == 0) ? (unsigned short)0x3F80 : (unsigned short)0;
    unsigned short tmp[8] = {vv, vv, vv, vv, vv, vv, vv, vv};
    *(int4*)(Ol + swzb(r, c)) = *(int4*)tmp;
  }
  // prologue: stage tile 0 into buffer 0
  {
    int4 sk0 = *(const int4*)(Kg + (long)srow * 512 + schk * 8);
    int4 sk1 = *(const int4*)(Kg + (long)(srow + 32) * 512 + schk * 8);
    int4 sv0 = *(const int4*)(Vg + (long)srow * 1024 + schk * 8);
    int4 sv1 = *(const int4*)(Vg + (long)(srow + 32) * 1024 + schk * 8);
    *(int4*)(Kl[0] + swzb(srow, schk)) = sk0;
    *(int4*)(Kl[0] + swzb(srow + 32, schk)) = sk1;
    *(int4*)(Vl[0] + swzb(srow, schk)) = sv0;
    *(int4*)(Vl[0] + swzb(srow + 32, schk)) = sv1;
  }
  __syncthreads();

  f32x4 po[2][5] = {};   // [qf][df]; df=4 = ones-column (row-sum at lc==0)

#pragma unroll 2
  for (int kt = 0; kt < 16; ++kt) {
    const int cur = kt & 1;
    const int kb = kt * 64;
    // issue next tile's coalesced global loads (written to LDS after compute)
    int4 nk0 = {}, nk1 = {}, nv0 = {}, nv1 = {};
    if (kt < 15) {
      const int kbn = kb + 64;
      nk0 = *(const int4*)(Kg + (long)(kbn + srow) * 512 + schk * 8);
      nk1 = *(const int4*)(Kg + (long)(kbn + srow + 32) * 512 + schk * 8);
      nv0 = *(const int4*)(Vg + (long)srow * 1024 + kbn + schk * 8);
      nv1 = *(const int4*)(Vg + (long)(srow + 32) * 1024 + kbn + schk * 8);
    }

    // K fragments from LDS (row = key, chunk = d/8)
    bf16x8 kfr[4][2];
#pragma unroll
    for (int kf = 0; kf < 4; ++kf)
#pragma unroll
      for (int dc = 0; dc < 2; ++dc)
        kfr[kf][dc] = *(const bf16x8*)(Kl[cur] + swzb(kf * 16 + lc, dc * 4 + g));

    // S = (Q*SCL) K^T
    f32x4 sv[2][4];
#pragma unroll
    for (int qf = 0; qf < 2; ++qf)
#pragma unroll
      for (int kf = 0; kf < 4; ++kf) {
        f32x4 a = {};
        a = __builtin_amdgcn_mfma_f32_16x16x32_bf16(qfr[qf][0], kfr[kf][0], a, 0, 0, 0);
        a = __builtin_amdgcn_mfma_f32_16x16x32_bf16(qfr[qf][1], kfr[kf][1], a, 0, 0, 0);
        sv[qf][kf] = a;
      }

    // mask (cndmask; scale pre-folded into Q), then exp2
#pragma unroll
    for (int kf = 0; kf < 4; ++kf) {
      int j = kb + kf * 16 + lc;
      int jr = j >> 5, jc = j & 31;
#pragma unroll
      for (int qf = 0; qf < 2; ++qf)
#pragma unroll
        for (int r = 0; r < 4; ++r) {
          bool ok = ((rm[qf * 4 + r] >> jr) & (cm[qf * 4 + r] >> jc) & 1) != 0;
          float s = ok ? sv[qf][kf][r] : -1.0e30f;
          sv[qf][kf][r] = fexp2(s);
        }
    }

    // V^T fragments from LDS (row = d, chunk = key'/8); df=4 from ones region
    bf16x8 vfr[5][2];
#pragma unroll
    for (int df = 0; df < 4; ++df)
#pragma unroll
      for (int kc = 0; kc < 2; ++kc)
        vfr[df][kc] = *(const bf16x8*)(Vl[cur] + swzb(df * 16 + lc, kc * 4 + g));
#pragma unroll
    for (int kc = 0; kc < 2; ++kc)
      vfr[4][kc] = *(const bf16x8*)(Ol + swzb(lc, kc * 4 + g));

    // P pack -> LDS b64 stores at col' = 4*lc (+kf), wave-private
#pragma unroll
    for (int qf = 0; qf < 2; ++qf)
#pragma unroll
      for (int r = 0; r < 4; ++r) {
        uint2 pk;
        pk.x = pk2bf(sv[qf][0][r], sv[qf][1][r]);
        pk.y = pk2bf(sv[qf][2][r], sv[qf][3][r]);
        *(uint2*)(&Plds[w][qf * 16 + g * 4 + r][4 * lc]) = pk;
      }

#pragma unroll
    for (int qf = 0; qf < 2; ++qf) {
      bf16x8 pa0 = *(const bf16x8*)(&Plds[w][qf * 16 + lc][g * 8]);
      bf16x8 pa1 = *(const bf16x8*)(&Plds[w][qf * 16 + lc][32 + g * 8]);
#pragma unroll
      for (int df = 0; df < 5; ++df) {
        po[qf][df] = __builtin_amdgcn_mfma_f32_16x16x32_bf16(pa0, vfr[df][0], po[qf][df], 0, 0, 0);
        po[qf][df] = __builtin_amdgcn_mfma_f32_16x16x32_bf16(pa1, vfr[df][1], po[qf][df], 0, 0, 0);
      }
    }

    // write staged next tile into the other buffer; one barrier per tile
    if (kt < 15) {
      const int nxt = cur ^ 1;
      *(int4*)(Kl[nxt] + swzb(srow, schk)) = nk0;
      *(int4*)(Kl[nxt] + swzb(srow + 32, schk)) = nk1;
      *(int4*)(Vl[nxt] + swzb(srow, schk)) = nv0;
      *(int4*)(Vl[nxt] + swzb(srow + 32, schk)) = nv1;
    }
    __syncthreads();
  }

  // epilogue: l = ones-column (lane lc==0 of each 16-group), normalize, write bf16
#pragma unroll
  for (int qf = 0; qf < 2; ++qf)
#pragma unroll
    for (int r = 0; r < 4; ++r) {
      float lsum = __shfl(po[qf][4][r], l & 48);
      float inv = 1.0f / lsum;
      long qr = qrow0 + qf * 16 + g * 4 + r;
#pragma unroll
      for (int df = 0; df < 4; ++df)
        Abf[qr * 512 + h * 64 + df * 16 + lc] = f2bf(po[qf][df][r] * inv);
    }
}

// ---- output projection: out = Abf @ Wot^T + bo (fp32 out) ----
__global__ __launch_bounds__(256) void gemm_o(const unsigned short* __restrict__ A,
                                              const unsigned short* __restrict__ Bt,
                                              float* __restrict__ C,
                                              const float* __restrict__ bias) {
  __shared__ unsigned short As[64][40];
  __shared__ unsigned short Bs[128][40];
  const int t = threadIdx.x, l = t & 63, wid = t >> 6;
  const int wr = (wid >> 1) << 5;
  const int wc = (wid & 1) << 6;
  const long tm = (long)blockIdx.x * 64;
  const long tn = (long)blockIdx.y * 128;
  f32x4 acc[2][4] = {};
  const int lr = l & 15, lk = (l >> 4) << 3;
  for (int k0 = 0; k0 < 512; k0 += 32) {
    {
      int e = t;
      int row = e >> 2, kg = (e & 3) << 3;
      if (row < 64)
        *(int4*)(&As[row][kg]) = *(const int4*)(A + (tm + row) * 512 + k0 + kg);
    }
#pragma unroll
    for (int p = 0; p < 2; ++p) {
      int e = t + (p << 8);
      int row = e >> 2, kg = (e & 3) << 3;
      *(int4*)(&Bs[row][kg]) = *(const int4*)(Bt + (tn + row) * 512 + k0 + kg);
    }
    __syncthreads();
    bf16x8 af[2], bfr[4];
#pragma unroll
    for (int i = 0; i < 2; ++i) af[i]  = *(const bf16x8*)(&As[wr + i * 16 + lr][lk]);
#pragma unroll
    for (int i = 0; i < 4; ++i) bfr[i] = *(const bf16x8*)(&Bs[wc + i * 16 + lr][lk]);
#pragma unroll
    for (int mi = 0; mi < 2; ++mi)
#pragma unroll
      for (int ni = 0; ni < 4; ++ni)
        acc[mi][ni] = __builtin_amdgcn_mfma_f32_16x16x32_bf16(af[mi], bfr[ni], acc[mi][ni], 0, 0, 0);
    __syncthreads();
  }
  const int lq = (l >> 4) << 2;
#pragma unroll
  for (int mi = 0; mi < 2; ++mi)
#pragma unroll
    for (int ni = 0; ni < 4; ++ni) {
      long col = tn + wc + ni * 16 + lr;
      float bv = bias[col];
      long r0 = tm + wr + mi * 16 + lq;
#pragma unroll
      for (int r = 0; r < 4; ++r)
        C[(r0 + r) * 512 + col] = acc[mi][ni][r] + bv;
    }
}

extern "C" void kernel_launch(void* const* d_in, const int* in_sizes, int n_in,
                              void* d_out, int out_size, void* d_ws, size_t ws_size,
                              hipStream_t stream) {
  (void)in_sizes; (void)n_in; (void)out_size; (void)ws_size;
  const float* feats   = (const float*)d_in[0];
  const int*   coords  = (const int*)d_in[1];
  const float* ctx     = (const float*)d_in[2];
  const float* Wq      = (const float*)d_in[3];
  const float* Wk      = (const float*)d_in[4];
  const float* Wv      = (const float*)d_in[5];
  const float* Wo      = (const float*)d_in[6];
  const float* bo      = (const float*)d_in[7];
  const float* pos_emb = (const float*)d_in[8];
  const float* ctx_pos = (const float*)d_in[9];
  float* out = (float*)d_out;
  char* ws = (char*)d_ws;

  unsigned short* Wqt = (unsigned short*)(ws);               //   524,288
  unsigned short* Wkt = (unsigned short*)(ws + 524288);
  unsigned short* Wvt = (unsigned short*)(ws + 1048576);
  unsigned short* Wot = (unsigned short*)(ws + 1572864);
  unsigned short* Qb  = (unsigned short*)(ws + 2097152);     // 8,388,608
  unsigned short* Kb  = (unsigned short*)(ws + 10485760);    // 4,194,304
  unsigned short* Vt  = (unsigned short*)(ws + 14680064);    // 4,194,304
  unsigned short* Abf = (unsigned short*)(ws + 18874368);    // 8,388,608 (end 27,262,976)

  prep_w  <<<4096, 256, 0, stream>>>(Wq, Wk, Wv, Wo, Wqt, Wkt, Wvt, Wot);
  gemm_qkv<<<1024, 256, 0, stream>>>(feats, coords, pos_emb, ctx, ctx_pos,
                                     Wqt, Wkt, Wvt, Qb, Kb, Vt);
  attn_mfma<<<dim3(16, 32), 256, 0, stream>>>(Qb, Kb, Vt, coords, Abf);
  gemm_o  <<<dim3(128, 4), 256, 0, stream>>>(Abf, Wot, out, bo);
}